// Round 1
// 108.400 us; speedup vs baseline: 1.0140x; 1.0140x over previous
//
#include <hip/hip_runtime.h>
#include <stdint.h>

#define NB 4096          // number of boxes
#define NBLK 64          // 64 blocks of 64 boxes
#define LLOC 16384       // number of locations
#define IOU_THR 0.5f
#define ECAP 1024        // entry capacity per source block bucket
#define RANKB 256        // rank blocks (16 boxes each)
#define NTRI (NBLK * (NBLK + 1) / 2)   // 2080 upper-triangle tiles

typedef unsigned long long u64;

__device__ __forceinline__ u64 readlane64(u64 v, int lane) {
    unsigned lo = (unsigned)__builtin_amdgcn_readlane((int)(unsigned)(v & 0xffffffffull), lane);
    unsigned hi = (unsigned)__builtin_amdgcn_readlane((int)(unsigned)(v >> 32), lane);
    return ((u64)hi << 32) | (u64)lo;
}

// ------- fused front: pred (0-63), rank (64-319, wave-per-box), maxc (320) ---
__global__ void __launch_bounds__(256) fused_front(
        const float* __restrict__ boxes, const float* __restrict__ scores,
        const float* __restrict__ loc, const float* __restrict__ deltas,
        const int* __restrict__ stride_p,
        float* __restrict__ pred_out, float* __restrict__ maxc,
        int* __restrict__ sidx, int* __restrict__ counts) {
    __shared__ __align__(16) float sh[NB];
    __shared__ float red[4];
    int blk = blockIdx.x;
    int t = threadIdx.x;

    if (blk < 64) {
        // ---- pred boxes + centerness ----
        int i = blk * 256 + t;
        float s = (float)stride_p[0];
        float2 p = ((const float2*)loc)[i];
        float4 d = ((const float4*)deltas)[i];
        float c0 = fmaxf(d.x, 0.f), c1 = fmaxf(d.y, 0.f);
        float c2 = fmaxf(d.z, 0.f), c3 = fmaxf(d.w, 0.f);
        float b0 = p.x - c0 * s;
        float b1 = p.y - c1 * s;
        float b2 = p.x + c2 * s;
        float b3 = p.y + c3 * s;
        float lr_min = fminf(d.x, d.z), tb_min = fminf(d.y, d.w);
        float lr_max = fmaxf(d.x, d.z), tb_max = fmaxf(d.y, d.w);
        float cent = sqrtf((lr_min * tb_min) / (lr_max * tb_max));
        if (d.x == -1.f && d.y == -1.f && d.z == -1.f && d.w == -1.f) cent = -1.f;
        float* o = pred_out + (size_t)i * 5;
        o[0] = b0; o[1] = b1; o[2] = b2; o[3] = b3; o[4] = cent;
    } else if (blk < 64 + RANKB) {
        // ---- rank: one wave per box, 4 boxes/wave, 64-iteration j-loop ----
        for (int i = t; i < NB; i += 256) sh[i] = scores[i];
        __syncthreads();
        int wave = t >> 6, lane = t & 63;
        int base = (blk - 64) * 16 + wave * 4;     // 4 consecutive boxes
        float my0 = sh[base + 0], my1 = sh[base + 1];
        float my2 = sh[base + 2], my3 = sh[base + 3];
        int c0 = 0, c1 = 0, c2 = 0, c3 = 0;
#pragma unroll 8
        for (int k = 0; k < 64; ++k) {
            int j = lane + k * 64;                 // 2-way LDS bank alias: free
            float sj = sh[j];
            c0 += (sj > my0) || (sj == my0 && j < base + 0);
            c1 += (sj > my1) || (sj == my1 && j < base + 1);
            c2 += (sj > my2) || (sj == my2 && j < base + 2);
            c3 += (sj > my3) || (sj == my3 && j < base + 3);
        }
        for (int o = 32; o > 0; o >>= 1) {
            c0 += __shfl_down(c0, o); c1 += __shfl_down(c1, o);
            c2 += __shfl_down(c2, o); c3 += __shfl_down(c3, o);
        }
        if (lane == 0) {
            sidx[c0] = base + 0; sidx[c1] = base + 1;
            sidx[c2] = base + 2; sidx[c3] = base + 3;
        }
    } else {
        // ---- max coordinate + zero bucket counters ----
        if (t < NBLK) counts[t] = 0;
        float m = -3.0e38f;
        for (int i = t; i < NB * 4; i += 256) m = fmaxf(m, boxes[i]);
        for (int o = 32; o > 0; o >>= 1) m = fmaxf(m, __shfl_down(m, o));
        if ((t & 63) == 0) red[t >> 6] = m;
        __syncthreads();
        if (t == 0) *maxc = fmaxf(fmaxf(red[0], red[1]), fmaxf(red[2], red[3]));
    }
}

// -------- sparse suppression-edge extraction, inline gather, triangular ------
// Off-diagonal entry: .x = local_row | (word_col<<8), .z/.w = 64-bit word.
// Bucketed by source block r; only nonzero words stored.
// Diagonal tiles write their row word DENSELY to dcol[r*64+t] (each slot
// written exactly once -> no atomics, no zeroing, no capacity risk).
__global__ void __launch_bounds__(64) edge_kernel(
        const float* __restrict__ boxes, const int* __restrict__ cls,
        const float* __restrict__ maxc, const int* __restrict__ sidx,
        int* __restrict__ counts, uint4* __restrict__ entries,
        u64* __restrict__ dcol) {
    // decode upper-triangle tile (r <= c) from linear block id (uniform scalar)
    int idx = blockIdx.x, r = 0;
    while (idx >= NBLK - r) { idx -= NBLK - r; ++r; }
    int c = r + idx;

    __shared__ float4 cb[64];
    __shared__ float ca[64];
    int t = threadIdx.x;                // 64 threads = one wave
    float mc1 = maxc[0] + 1.0f;

    // gather row-tile box (sorted order) for this lane
    int jr = sidx[r * 64 + t];
    float offr = (float)cls[jr] * mc1;
    float4 rb = ((const float4*)boxes)[jr];
    rb.x += offr; rb.y += offr; rb.z += offr; rb.w += offr;
    float ra = (rb.z - rb.x) * (rb.w - rb.y);

    // column tile into LDS (reuse row tile when on the diagonal)
    if (c == r) {
        cb[t] = rb; ca[t] = ra;
    } else {
        int jc = sidx[c * 64 + t];
        float offc = (float)cls[jc] * mc1;
        float4 b = ((const float4*)boxes)[jc];
        b.x += offc; b.y += offc; b.z += offc; b.w += offc;
        cb[t] = b; ca[t] = (b.z - b.x) * (b.w - b.y);
    }
    __syncthreads();

    u64 w = 0;
#pragma unroll 8
    for (int j = 0; j < 64; ++j) {
        float4 b = cb[j];
        float xi = fminf(rb.z, b.z) - fmaxf(rb.x, b.x);
        float yi = fminf(rb.w, b.w) - fmaxf(rb.y, b.y);
        float inter = fmaxf(xi, 0.f) * fmaxf(yi, 0.f);
        float iou = inter / (ra + ca[j] - inter);
        w |= (u64)(iou > IOU_THR) << j;
    }
    if (c == r) {
        w &= ~(1ull << t);              // drop self-overlap bit
        dcol[r * 64 + t] = w;           // dense diagonal word, written once
    } else if (w) {
        int slot = atomicAdd(&counts[r], 1);
        if (slot < ECAP)
            entries[r * ECAP + slot] =
                make_uint4((unsigned)(t | (c << 8)), 0u,
                           (unsigned)(w & 0xffffffffull), (unsigned)(w >> 32));
    }
}

// ---------------- serial greedy scan over sparse edges ----------------------
// Wave 0 runs the serial 64-block loop; removed-mask lives in LDS so the
// kept-row merge (pass 2) is one lane-parallel atomicOr instead of a serial
// readlane loop. Waves 1-3 join for a 4-wave scattered-store epilogue.
__global__ void __launch_bounds__(256) scan_kernel(
        const int* __restrict__ counts, const uint4* __restrict__ entries,
        const u64* __restrict__ dcol, const int* __restrict__ sidx,
        float* __restrict__ keep_out) {
    __shared__ u64 rem_lds[NBLK];       // removed-mask per block (4096 bits)
    __shared__ u64 kept_lds[NBLK];      // kept-mask per block
    const int t = threadIdx.x;
    const int lane = t & 63;

    if (t < 64) {
        rem_lds[t] = 0;
        int cnt_l = counts[lane];       // lane b holds block b's entry count
        u64 keptall_w = 0;
        u64 self = 1ull << lane;

        // depth-2 prefetch: covers cross-XCD L2-miss latency (~600-900 cyc)
        uint4 cur = entries[lane];
        uint4 n1  = entries[ECAP + lane];
        u64 cw_cur = dcol[lane];        // lane j: diagonal word of box j, blk 0
        u64 cw_n1  = dcol[64 + lane];
        for (int b = 0; b < NBLK; ++b) {
            uint4 n2; u64 cw_n2;
            if (b < NBLK - 2) {
                n2    = entries[(u64)(b + 2) * ECAP + lane];
                cw_n2 = dcol[(b + 2) * 64 + lane];
            }

            int cnt = __builtin_amdgcn_readlane(cnt_l, b);
            if (cnt > ECAP) cnt = ECAP;

            // within-block column words: direct from the dense diagonal table
            u64 colw = self | cw_cur;

            // decision: optimistic ballot; serial greedy only over conflicts.
            // rem_lds[b] broadcast-read; same-wave DS ops retire in order, so
            // all pass-2 atomicOrs from earlier iterations are visible.
            u64 rem = rem_lds[b];
            u64 avail = ~rem;
            u64 edges = colw & avail & ~self;
            u64 involved = __ballot(edges != 0ull) & avail;
            u64 keptm = avail & ~involved;
            u64 sub = involved;
            while (sub) {
                int i = (int)__builtin_ctzll(sub);   // highest score first
                keptm |= 1ull << i;
                u64 ci = readlane64(colw, i);
                sub &= ~(ci | (1ull << i));
            }
            if (lane == b) keptall_w = keptm;

            // pass 2, lane-parallel: lane e already holds entry e (prefetch).
            // keptm is wave-uniform -> each lane merges its own entry.
            if (lane < cnt) {
                int l = cur.x & 255, c = cur.x >> 8;
                if ((keptm >> l) & 1ull)
                    atomicOr(&rem_lds[c], ((u64)cur.w << 32) | cur.z);
            }
            for (int e = 64; e < cnt; e += 64) {     // overflow path (rare)
                int ee = e + lane;
                if (ee < cnt) {
                    uint4 x = entries[(u64)b * ECAP + ee];
                    int l = x.x & 255, c = x.x >> 8;
                    if ((keptm >> l) & 1ull)
                        atomicOr(&rem_lds[c], ((u64)x.w << 32) | x.z);
                }
            }
            cur = n1; n1 = n2; cw_cur = cw_n1; cw_n1 = cw_n2;
        }
        kept_lds[lane] = keptall_w;     // lane b publishes block b's kept mask
    }
    __syncthreads();

    // epilogue: 4 waves x 16 iterations, scattered stores via sorted index
    int w = t >> 6;
#pragma unroll
    for (int k = 0; k < 16; ++k) {
        int bb = w + k * 4;
        u64 kw = kept_lds[bb];                   // LDS broadcast read
        int idx = sidx[bb * 64 + lane];          // coalesced load
        keep_out[idx] = ((kw >> lane) & 1ull) ? 1.0f : 0.0f;
    }
}

extern "C" void kernel_launch(void* const* d_in, const int* in_sizes, int n_in,
                              void* d_out, int out_size, void* d_ws, size_t ws_size,
                              hipStream_t stream) {
    const float* boxes   = (const float*)d_in[0];   // (4096,4)
    const float* scores  = (const float*)d_in[1];   // (4096,)
    const int*   cls     = (const int*)d_in[2];     // (4096,)
    const float* loc     = (const float*)d_in[3];   // (16384,2)
    const float* deltas  = (const float*)d_in[4];   // (16384,4)
    const int*   stride  = (const int*)d_in[5];     // scalar

    float* out = (float*)d_out;
    float* keep_out = out;          // 4096 floats (bool as 0/1)
    float* pred_out = out + NB;     // 16384*5 floats

    // workspace layout (16B-aligned pieces), ~1.08 MiB total
    char* ws = (char*)d_ws;
    float* maxc    = (float*)ws;                     ws += 16;
    int*   sidx    = (int*)ws;                       ws += NB * sizeof(int);
    int*   counts  = (int*)ws;                       ws += NBLK * sizeof(int) + 16;
    uint4* entries = (uint4*)ws;                     ws += (size_t)NBLK * ECAP * sizeof(uint4);
    u64*   dcol    = (u64*)ws;                       // NBLK*64*8 B = 32 KiB

    fused_front<<<64 + RANKB + 1, 256, 0, stream>>>(boxes, scores, loc, deltas, stride,
                                                    pred_out, maxc, sidx, counts);
    edge_kernel<<<NTRI, 64, 0, stream>>>(boxes, cls, maxc, sidx, counts, entries, dcol);
    scan_kernel<<<1, 256, 0, stream>>>(counts, entries, dcol, sidx, keep_out);
}